// Round 1
// baseline (255.874 us; speedup 1.0000x reference)
//
#include <hip/hip_runtime.h>
#include <stdint.h>
#include <stddef.h>

typedef __attribute__((ext_vector_type(8))) short s8v;       // 8 x bf16 (as i16)
typedef __attribute__((ext_vector_type(4))) float f32x4;
typedef __attribute__((ext_vector_type(4))) uint32_t u32x4;
typedef __attribute__((ext_vector_type(4))) unsigned short u16x4;

#define KDIM 4096
#define NH   128
#define BM   128
#define BK   64
#define NK   (KDIM / BK)
#define MMEM 50000
#define BFEAT 64

static __device__ __forceinline__ unsigned short f2bf(float f) {
  union { float f; uint32_t u; } c; c.f = f;
  uint32_t u = c.u;
  return (unsigned short)((u + 0x7FFFu + ((u >> 16) & 1u)) >> 16);  // RNE
}

// ---- Kernel 0: hash_W f32 -> bf16 ------------------------------------------
__global__ __launch_bounds__(256) void convert_w_kernel(
    const float* __restrict__ W, unsigned short* __restrict__ Wb) {
  int i = blockIdx.x * 256 + threadIdx.x;          // float4 index, 131072 total
  f32x4 v = reinterpret_cast<const f32x4*>(W)[i];
  u16x4 o;
  o[0] = f2bf(v[0]); o[1] = f2bf(v[1]); o[2] = f2bf(v[2]); o[3] = f2bf(v[3]);
  reinterpret_cast<u16x4*>(Wb)[i] = o;
}

// ---- Kernel A: bf16 MFMA GEMM (A[M,4096] x Wb[128,4096]^T) -> packed bits ---
__global__ __launch_bounds__(256, 2) void hash_bits_kernel(
    const float* __restrict__ A, int M,
    const unsigned short* __restrict__ Wb,
    const float* __restrict__ hb,
    uint32_t* __restrict__ out_bits) {
  __shared__ short As[2][BM * BK];
  __shared__ short Bs[2][BM * BK];

  const int t    = threadIdx.x;
  const int lane = t & 63;
  const int w    = t >> 6;
  const int wr   = w >> 1;
  const int wc   = w & 1;
  const int bm0  = blockIdx.x * BM;

  f32x4 acc[4][4];
#pragma unroll
  for (int i = 0; i < 4; ++i)
#pragma unroll
    for (int j = 0; j < 4; ++j) acc[i][j] = (f32x4){0.f, 0.f, 0.f, 0.f};

  f32x4 areg[4][2];
  s8v breg[4];

  // staging geometry: granule idx = t + 256*c -> row = idx>>3, g = idx&7
  int srow[4], sg[4];
#pragma unroll
  for (int c = 0; c < 4; ++c) {
    int idx = t + 256 * c;
    srow[c] = idx >> 3;
    sg[c]   = idx & 7;
  }

  auto issueAB = [&](int kt) {
#pragma unroll
    for (int c = 0; c < 4; ++c) {
      int arow = bm0 + srow[c];
      if (arow > M - 1) arow = M - 1;                  // clamp tail rows
      const f32x4* pa = reinterpret_cast<const f32x4*>(A + (size_t)arow * KDIM + kt + sg[c] * 8);
      areg[c][0] = pa[0];
      areg[c][1] = pa[1];
      breg[c] = *reinterpret_cast<const s8v*>(Wb + (size_t)srow[c] * KDIM + kt + sg[c] * 8);
    }
  };
  auto writeAB = [&](int buf) {
#pragma unroll
    for (int c = 0; c < 4; ++c) {
      int off = srow[c] * BK + ((sg[c] ^ (srow[c] & 7)) << 3);   // T2 XOR swizzle
      s8v av;
#pragma unroll
      for (int q = 0; q < 4; ++q) {
        av[q]     = (short)f2bf(areg[c][0][q]);
        av[q + 4] = (short)f2bf(areg[c][1][q]);
      }
      *reinterpret_cast<s8v*>(&As[buf][off]) = av;
      *reinterpret_cast<s8v*>(&Bs[buf][off]) = breg[c];
    }
  };

  issueAB(0);
  writeAB(0);
  __syncthreads();

  const int l15 = lane & 15;
  const int kq  = (lane >> 4) * 8;

  for (int ki = 0; ki < NK; ++ki) {
    const int cur = ki & 1;
    if (ki + 1 < NK) issueAB((ki + 1) * BK);   // loads in flight across MFMA phase
#pragma unroll
    for (int kk = 0; kk < 2; ++kk) {
      const int kg = (kk * 32 + kq) >> 3;
      s8v af[4], bfr[4];
#pragma unroll
      for (int i = 0; i < 4; ++i) {
        int row = wr * 64 + i * 16 + l15;
        af[i] = *reinterpret_cast<const s8v*>(&As[cur][row * BK + ((kg ^ (row & 7)) << 3)]);
      }
#pragma unroll
      for (int j = 0; j < 4; ++j) {
        int row = wc * 64 + j * 16 + l15;
        bfr[j] = *reinterpret_cast<const s8v*>(&Bs[cur][row * BK + ((kg ^ (row & 7)) << 3)]);
      }
#pragma unroll
      for (int i = 0; i < 4; ++i)
#pragma unroll
        for (int j = 0; j < 4; ++j)
          acc[i][j] = __builtin_amdgcn_mfma_f32_16x16x32_bf16(af[i], bfr[j], acc[i][j], 0, 0, 0);
    }
    if (ki + 1 < NK) {
      writeAB(cur ^ 1);
      __syncthreads();
    }
  }

  // ---- epilogue: sign bits -> LDS bitmap -> packed u32 words ----
  __syncthreads();
  unsigned char* bmap = reinterpret_cast<unsigned char*>(&As[0][0]);  // 16 KB reuse
#pragma unroll
  for (int j = 0; j < 4; ++j) {
    int col = wc * 64 + j * 16 + l15;
    float hbv = hb[col];
#pragma unroll
    for (int i = 0; i < 4; ++i) {
      int rbase = wr * 64 + i * 16 + (lane >> 4) * 4;
#pragma unroll
      for (int r = 0; r < 4; ++r) {
        float v = acc[i][j][r] + hbv - 0.5f;
        bmap[(rbase + r) * NH + col] = (v > 0.f) ? 1 : 0;
      }
    }
  }
  __syncthreads();
  {
    int row  = t >> 1;
    int grow = bm0 + row;
    if (grow < M) {
#pragma unroll
      for (int h = 0; h < 2; ++h) {
        int wdx = (t & 1) * 2 + h;
        uint32_t bits = 0;
        const unsigned char* p = &bmap[row * NH + wdx * 32];
#pragma unroll
        for (int c2 = 0; c2 < 32; ++c2) bits |= (uint32_t)(p[c2] & 1u) << c2;
        out_bits[(size_t)grow * 4 + wdx] = bits;
      }
    }
  }
}

// ---- Kernel hf: fp32 feature codes (tiny: 64x128 dots of length 4096) -------
__global__ __launch_bounds__(64) void hf_kernel(
    const float* __restrict__ flat, const float* __restrict__ W,
    const float* __restrict__ hb, unsigned char* __restrict__ hf_bytes) {
  int bid = blockIdx.x;            // 8192 = 64 b * 128 n
  int n = bid & 127, b = bid >> 7;
  int lane = threadIdx.x;
  const f32x4* fa = reinterpret_cast<const f32x4*>(flat + (size_t)b * KDIM);
  const f32x4* wa = reinterpret_cast<const f32x4*>(W + (size_t)n * KDIM);
  float s = 0.f;
#pragma unroll 4
  for (int q = 0; q < 16; ++q) {
    f32x4 x = fa[lane + 64 * q], y = wa[lane + 64 * q];
    s += x[0] * y[0] + x[1] * y[1] + x[2] * y[2] + x[3] * y[3];
  }
  for (int o = 32; o; o >>= 1) s += __shfl_down(s, o, 64);
  if (lane == 0) hf_bytes[b * NH + n] = (s + hb[n] - 0.5f) > 0.f ? 1 : 0;
}

// ---- Kernel B: per-batch argmin Hamming with first-index tie-break ----------
__global__ __launch_bounds__(256) void argmin_kernel(
    const uint32_t* __restrict__ hm_bits, const unsigned char* __restrict__ hf_bytes,
    int M, int* __restrict__ out_idx) {
  __shared__ uint32_t red[256];
  const int b = blockIdx.x;
  const int t = threadIdx.x;
  uint64_t hf0 = 0, hf1 = 0;
  const unsigned char* hfb = hf_bytes + b * NH;
  for (int c = 0; c < 64; ++c) {
    hf0 |= (uint64_t)(hfb[c] & 1u) << c;
    hf1 |= (uint64_t)(hfb[c + 64] & 1u) << c;
  }
  int hfsum = __popcll(hf0) + __popcll(hf1);
  uint32_t best = 0xFFFFFFFFu;
  for (int m = t; m < M; m += 256) {
    u32x4 pv = reinterpret_cast<const u32x4*>(hm_bits)[m];
    uint64_t h0 = (uint64_t)pv[0] | ((uint64_t)pv[1] << 32);
    uint64_t h1 = (uint64_t)pv[2] | ((uint64_t)pv[3] << 32);
    int hmsum = __popcll(h0) + __popcll(h1);
    int dot   = __popcll(h0 & hf0) + __popcll(h1 & hf1);
    int hd    = hfsum + hmsum - 2 * dot;
    uint32_t key = ((uint32_t)hd << 16) | (uint32_t)m;   // M < 65536, HD <= 256
    best = best < key ? best : key;
  }
  red[t] = best;
  __syncthreads();
  for (int s = 128; s > 0; s >>= 1) {
    if (t < s) red[t] = red[t] < red[t + s] ? red[t] : red[t + s];
    __syncthreads();
  }
  if (t == 0) out_idx[b] = (int)(red[0] & 0xFFFFu);
}

// ---- Kernel C: gather nearest memory rows -----------------------------------
__global__ __launch_bounds__(256) void gather_kernel(
    const float* __restrict__ memory, const int* __restrict__ idx,
    float* __restrict__ out) {
  int b = blockIdx.x;
  int t = threadIdx.x;
  int m = idx[b];
  const f32x4* src = reinterpret_cast<const f32x4*>(memory + (size_t)m * KDIM);
  f32x4* dst = reinterpret_cast<f32x4*>(out + (size_t)b * KDIM);
#pragma unroll
  for (int c = 0; c < 4; ++c) dst[t + 256 * c] = src[t + 256 * c];
}

extern "C" void kernel_launch(void* const* d_in, const int* in_sizes, int n_in,
                              void* d_out, int out_size, void* d_ws, size_t ws_size,
                              hipStream_t stream) {
  const float* feature = (const float*)d_in[0];   // [64,64,8,8] == [64,4096]
  const float* memory  = (const float*)d_in[1];   // [50000,4096]
  const float* hash_W  = (const float*)d_in[2];   // [128,4096]
  const float* hash_b  = (const float*)d_in[3];   // [128]
  float* out = (float*)d_out;

  char* ws = (char*)d_ws;
  unsigned short* Wb       = (unsigned short*)ws;                       // 1,048,576 B
  uint32_t*       hm_bits  = (uint32_t*)(ws + 1048576);                 //   800,000 B
  unsigned char*  hf_bytes = (unsigned char*)(ws + 1048576 + 800000);   //     8,192 B
  int*            idxbuf   = (int*)(ws + 1048576 + 800000 + 8192);      //       256 B

  convert_w_kernel<<<(NH * KDIM / 4) / 256, 256, 0, stream>>>(hash_W, Wb);
  hash_bits_kernel<<<(MMEM + BM - 1) / BM, 256, 0, stream>>>(memory, MMEM, Wb, hash_b, hm_bits);
  hf_kernel<<<BFEAT * NH, 64, 0, stream>>>(feature, hash_W, hash_b, hf_bytes);
  argmin_kernel<<<BFEAT, 256, 0, stream>>>(hm_bits, hf_bytes, MMEM, idxbuf);
  gather_kernel<<<BFEAT, 256, 0, stream>>>(memory, idxbuf, out);
}